// Round 6
// baseline (228.809 us; speedup 1.0000x reference)
//
#include <hip/hip_runtime.h>
#include <hip/hip_bf16.h>
#include <math.h>

// Problem constants: B=8, C=256, CQ=32, N=H*W=4096
constexpr int B_ = 8;
constexpr int C_ = 256;
constexpr int CQ_ = 32;
constexpr int N_ = 4096;
constexpr int FP = 40;            // padded pitch (shorts) for 32-wide rows: bank-clean

typedef __attribute__((ext_vector_type(8))) short short8;   // 8 bf16
typedef __attribute__((ext_vector_type(4))) float f32x4;    // MFMA C/D

__device__ __forceinline__ unsigned short pk1(float a) {
    __hip_bfloat16 h = __float2bfloat16(a);
    return *reinterpret_cast<unsigned short*>(&h);
}
__device__ __forceinline__ unsigned pk2(float a, float b) {
    __hip_bfloat162 h = __float22bfloat162_rn(float2{a, b});
    return *reinterpret_cast<unsigned*>(&h);
}

// async global->LDS, 16B per lane (dest = wave-uniform base + lane*16)
__device__ __forceinline__ void async16(const unsigned short* g, unsigned short* l) {
    __builtin_amdgcn_global_load_lds(
        (const __attribute__((address_space(1))) unsigned int*)g,
        (__attribute__((address_space(3))) unsigned int*)l, 16, 0, 0);
}

// ---------------------------------------------------------------------------
// prep (merged): blocks 0..2047 transpose feat -> featT [b][ks][n][ci&31] pitch 40;
// blocks 2048..2079: w1/w2 -> wqk pitch 264 ; w3 -> w3t [ks][c][ci&31] pitch 40
// ---------------------------------------------------------------------------
__global__ __launch_bounds__(256) void prep(
    const float* __restrict__ feat,
    const float* __restrict__ w1, const float* __restrict__ w2,
    const float* __restrict__ w3,
    unsigned short* __restrict__ featT,
    unsigned short* __restrict__ wqk, unsigned short* __restrict__ w3t)
{
    __shared__ float sh[64][65];
    int id = blockIdx.x;
    int t = threadIdx.x;

    if (id < 2048) {
        int b = id >> 8, r = id & 255;
        int n0 = (r >> 2) * 64, c0 = (r & 3) * 64;
        int nl = t & 63, cb = t >> 6;
#pragma unroll
        for (int i = 0; i < 16; ++i) {
            int cl = cb + i * 4;
            sh[cl][nl] = feat[((size_t)b * C_ + c0 + cl) * N_ + n0 + nl];
        }
        __syncthreads();
        int c2 = (t & 31) * 2, nb = t >> 5;
#pragma unroll
        for (int j = 0; j < 8; ++j) {
            int n = nb + j * 8;
            unsigned pv = pk2(sh[c2][n], sh[c2 + 1][n]);
            int cg = c0 + c2;
            int ks = cg >> 5, cij = cg & 31;
            *reinterpret_cast<unsigned*>(
                &featT[(((size_t)b * 8 + ks) * N_ + n0 + n) * FP + cij]) = pv;
        }
    } else {
        int tid = (id - 2048) * 256 + t;
        const int stride = 32 * 256;
        for (int f = tid; f < 2 * 32 * 256; f += stride) {
            int mat = f >> 13, rest = f & 8191;
            int o = rest >> 8, ci = rest & 255;
            const float* w = mat ? w2 : w1;
            wqk[(mat * 32 + o) * 264 + ci] = pk1(w[o * 256 + ci]);
        }
        for (int f = tid; f < 256 * 256; f += stride) {
            int c = f >> 8, ci = f & 255;
            w3t[((size_t)(ci >> 5) * 256 + c) * FP + (ci & 31)] = pk1(w3[f]);
        }
    }
}

// ---------------------------------------------------------------------------
// proj (merged): blocks 0..255 = qk (128 n rows) -> qT + kfrag;
//                blocks 256..767 = v (64-n tile) -> vfrag.
// kfrag[b][t32][sub2][lane64][8]: lane (col,grp) holds K[n=t*32+sub*16+col][cq=grp*8+j]
// vfrag[b][t32][cg16][lane64][8]: lane (col,grp) holds V[c=cg*16+col][nloc=grp*8+j]
// ---------------------------------------------------------------------------
__global__ __launch_bounds__(256) void proj(
    const unsigned short* __restrict__ featT, const unsigned short* __restrict__ wqk,
    const unsigned short* __restrict__ w3t,
    const float* __restrict__ b1, const float* __restrict__ b2,
    const float* __restrict__ b3,
    unsigned short* __restrict__ qT, unsigned short* __restrict__ kfrag,
    unsigned short* __restrict__ vfrag)
{
    __shared__ __align__(16) unsigned short smem[23552];   // 47,104 B
    int id = blockIdx.x;
    int t = threadIdx.x, lane = t & 63;
    int wu = t >> 6, col = lane & 15, grp = lane >> 4;

    if (id < 256) {
        // ---------------- qk branch ----------------
        unsigned short* wsl = smem;           // 18,432 shorts (pitch 264)
        unsigned short* fa  = smem + 18432;   //  5,120 shorts (128 rows x 40)
        int b = id >> 5, n0 = (id & 31) * 128;

#pragma unroll
        for (int i = 0; i < 9; ++i)
            async16(wqk + wu * 4608 + i * 512 + lane * 8, wsl + wu * 4608 + i * 512);

        f32x4 acc[2][2][2];  // [msub][mat][ot]
#pragma unroll
        for (int ms = 0; ms < 2; ++ms)
#pragma unroll
            for (int ot = 0; ot < 2; ++ot) {
                float bq = b1[ot * 16 + col];
                float bk = b2[ot * 16 + col];
                acc[ms][0][ot] = (f32x4){bq, bq, bq, bq};
                acc[ms][1][ot] = (f32x4){bk, bk, bk, bk};
            }

        for (int ks = 0; ks < 8; ++ks) {
            __syncthreads();
            const unsigned short* src = featT + (((size_t)b * 8 + ks) * N_ + n0) * FP;
            // 128*40 = 5120 shorts = 10 chunks of 512
#pragma unroll
            for (int i = 0; i < 3; ++i) {
                int ch = i * 4 + wu;
                if (ch < 10) async16(src + ch * 512 + lane * 8, fa + ch * 512);
            }
            __syncthreads();

            short8 a[2], bf[2][2];
#pragma unroll
            for (int ms = 0; ms < 2; ++ms)
                a[ms] = *(const short8*)&fa[(wu * 32 + ms * 16 + col) * FP + grp * 8];
#pragma unroll
            for (int mat = 0; mat < 2; ++mat)
#pragma unroll
                for (int ot = 0; ot < 2; ++ot)
                    bf[mat][ot] = *(const short8*)
                        &wsl[(mat * 32 + ot * 16 + col) * 264 + ks * 32 + grp * 8];
#pragma unroll
            for (int ms = 0; ms < 2; ++ms)
#pragma unroll
                for (int mat = 0; mat < 2; ++mat)
#pragma unroll
                    for (int ot = 0; ot < 2; ++ot)
                        acc[ms][mat][ot] = __builtin_amdgcn_mfma_f32_16x16x32_bf16(
                            a[ms], bf[mat][ot], acc[ms][mat][ot], 0, 0, 0);
        }

#pragma unroll
        for (int ms = 0; ms < 2; ++ms)
#pragma unroll
            for (int ot = 0; ot < 2; ++ot)
#pragma unroll
                for (int r = 0; r < 4; ++r) {
                    int n = n0 + wu * 32 + ms * 16 + grp * 4 + r;
                    int o = ot * 16 + col;
                    qT[((size_t)b * N_ + n) * 32 + o] = pk1(acc[ms][0][ot][r]);
                    // kfrag scatter: tile=n>>5, sub=(n>>4)&1, lane'=(o>>3)*16+(n&15), j=o&7
                    kfrag[(((size_t)b * 128 + (n >> 5)) * 2 + ((n >> 4) & 1)) * 512
                          + ((o >> 3) * 16 + (n & 15)) * 8 + (o & 7)]
                        = pk1(acc[ms][1][ot][r]);
                }
    } else {
        // ---------------- v branch ----------------
        unsigned short* w3s = smem;           // 10,240 shorts (256 rows x 40)
        unsigned short* fb  = smem + 10240;   //  2,560 shorts (64 rows x 40)
        int vid = id - 256;
        int b = vid >> 6, tile = vid & 63, n0 = tile * 64;

        f32x4 acc[4][4];  // [ct][nsub]
#pragma unroll
        for (int ct = 0; ct < 4; ++ct) {
            int c = wu * 64 + ct * 16 + grp * 4;
            float4 bb = *(const float4*)&b3[c];
            f32x4 ini = (f32x4){bb.x, bb.y, bb.z, bb.w};
#pragma unroll
            for (int ns = 0; ns < 4; ++ns) acc[ct][ns] = ini;
        }

        for (int ks = 0; ks < 8; ++ks) {
            __syncthreads();
            const unsigned short* wsrc = w3t + (size_t)ks * 256 * FP;
#pragma unroll
            for (int i = 0; i < 5; ++i) {
                int ch = wu * 5 + i;
                async16(wsrc + ch * 512 + lane * 8, w3s + ch * 512);
            }
            const unsigned short* fsrc = featT + (((size_t)b * 8 + ks) * N_ + n0) * FP;
#pragma unroll
            for (int i = 0; i < 2; ++i) {
                int ch = i * 4 + wu;
                if (ch < 5) async16(fsrc + ch * 512 + lane * 8, fb + ch * 512);
            }
            __syncthreads();

            short8 a[4], bfr[4];
#pragma unroll
            for (int ct = 0; ct < 4; ++ct)
                a[ct] = *(const short8*)&w3s[(wu * 64 + ct * 16 + col) * FP + grp * 8];
#pragma unroll
            for (int ns = 0; ns < 4; ++ns)
                bfr[ns] = *(const short8*)&fb[(ns * 16 + col) * FP + grp * 8];
#pragma unroll
            for (int ct = 0; ct < 4; ++ct)
#pragma unroll
                for (int ns = 0; ns < 4; ++ns)
                    acc[ct][ns] = __builtin_amdgcn_mfma_f32_16x16x32_bf16(
                        a[ct], bfr[ns], acc[ct][ns], 0, 0, 0);
        }

        // vfrag scatter: vt=n>>5, cg=c>>4, lane'=((n>>3)&3)*16+(c&15), j=n&7
#pragma unroll
        for (int ct = 0; ct < 4; ++ct)
#pragma unroll
            for (int ns = 0; ns < 4; ++ns)
#pragma unroll
                for (int r = 0; r < 4; ++r) {
                    int c = wu * 64 + ct * 16 + grp * 4 + r;
                    int n = n0 + ns * 16 + col;
                    vfrag[((((size_t)b * 128 + (n >> 5)) * 16 + (c >> 4)) * 64
                           + ((n >> 3) & 3) * 16 + (c & 15)) * 8 + (n & 7)]
                        = pk1(acc[ct][ns][r]);
                }
    }
}

// ---------------------------------------------------------------------------
// attn: flash attention, no-max softmax. NO K/V LDS — fragment-image loads
// global->VGPR (coalesced 16B/lane). ps double-buffered, ONE light barrier/iter
// (s_waitcnt lgkmcnt(0); s_barrier — no vmcnt drain). Next-iter K/V register
// prefetch issued before the barrier. Block = (64 m, b, c-half), 4 waves,
// wave owns 32 channels. Grid 1024 -> 4 blocks/CU (16 waves/CU).
// ---------------------------------------------------------------------------
__global__ __launch_bounds__(256, 4) void attn(
    const unsigned short* __restrict__ qT, const unsigned short* __restrict__ kfrag,
    const unsigned short* __restrict__ vfrag, const float* __restrict__ feat,
    const float* __restrict__ gamma, float* __restrict__ out)
{
    constexpr int PP = 40;  // ps pitch (shorts): 80 B — 16B-aligned rows, 2-way banks
    __shared__ __align__(16) unsigned short ps[2][64 * PP];  // 10,240 B
    __shared__ float lrow[64];

    const int m0 = blockIdx.x * 64;
    const int b  = blockIdx.y;
    const int ch = blockIdx.z;                 // channel half (128 c)
    int t0 = threadIdx.x, lane = t0 & 63;
    int wu = t0 >> 6, col = lane & 15, grp = lane >> 4;

    const int m_own = m0 + wu * 16 + col;      // this wave's S column
    short8 qf = *(const short8*)&qT[((size_t)b * N_ + m_own) * 32 + grp * 8];

    const int cgb = ch * 8 + wu * 2;           // wave's first 16-ch V group

    const unsigned short* kb = kfrag + (size_t)b * 128 * 2 * 512;
    const unsigned short* vb = vfrag + (size_t)b * 128 * 16 * 512;

    f32x4 acc[2][4];   // [ct][msub]
#pragma unroll
    for (int i = 0; i < 2; ++i)
#pragma unroll
        for (int j = 0; j < 4; ++j) acc[i][j] = (f32x4){0.f, 0.f, 0.f, 0.f};
    float l_run = 0.f;

    // prologue: fragment loads for tile 0
    short8 kf0 = *(const short8*)&kb[lane * 8];
    short8 kf1 = *(const short8*)&kb[512 + lane * 8];
    short8 vf0 = *(const short8*)&vb[(size_t)(cgb + 0) * 512 + lane * 8];
    short8 vf1 = *(const short8*)&vb[(size_t)(cgb + 1) * 512 + lane * 8];

    for (int t = 0; t < 128; ++t) {
        // ---- S^T (32n x 16m this wave) ----
        f32x4 z = (f32x4){0.f, 0.f, 0.f, 0.f};
        f32x4 d0 = __builtin_amdgcn_mfma_f32_16x16x32_bf16(kf0, qf, z, 0, 0, 0);
        f32x4 d1 = __builtin_amdgcn_mfma_f32_16x16x32_bf16(kf1, qf, z, 0, 0, 0);

        // ---- softmax numerators (no max subtraction; |s| <~ 12) ----
        float p0 = __expf(d0[0]), p1 = __expf(d0[1]);
        float p2 = __expf(d0[2]), p3 = __expf(d0[3]);
        float p4 = __expf(d1[0]), p5 = __expf(d1[1]);
        float p6 = __expf(d1[2]), p7 = __expf(d1[3]);
        float ptot = ((p0 + p1) + (p2 + p3)) + ((p4 + p5) + (p6 + p7));
        ptot += __shfl_xor(ptot, 16);
        ptot += __shfl_xor(ptot, 32);
        l_run += ptot;

        unsigned short* pw = &ps[t & 1][(wu * 16 + col) * PP];
        uint2 w0; w0.x = pk2(p0, p1); w0.y = pk2(p2, p3);
        uint2 w1; w1.x = pk2(p4, p5); w1.y = pk2(p6, p7);
        *reinterpret_cast<uint2*>(pw + grp * 4)      = w0;   // n = grp*4..+3
        *reinterpret_cast<uint2*>(pw + 16 + grp * 4) = w1;   // n = 16+grp*4..+3

        // ---- prefetch next tile's fragments (ride through the barrier) ----
        int tn = (t + 1) & 127;
        short8 kf0n = *(const short8*)&kb[(size_t)tn * 1024 + lane * 8];
        short8 kf1n = *(const short8*)&kb[(size_t)tn * 1024 + 512 + lane * 8];
        short8 vf0n = *(const short8*)&vb[((size_t)tn * 16 + cgb + 0) * 512 + lane * 8];
        short8 vf1n = *(const short8*)&vb[((size_t)tn * 16 + cgb + 1) * 512 + lane * 8];

        // light barrier: drain own LDS ops only — NO vmcnt(0) drain
        __asm__ volatile("s_waitcnt lgkmcnt(0)\n\ts_barrier" ::: "memory");

        // ---- P fragments (full 64 m) ----
        const unsigned short* pr = ps[t & 1];
        short8 pf[4];
#pragma unroll
        for (int ms = 0; ms < 4; ++ms)
            pf[ms] = *(const short8*)&pr[(ms * 16 + col) * PP + grp * 8];

        // ---- O^T += V^T · P^T (wave owns 32 channels) ----
#pragma unroll
        for (int ms = 0; ms < 4; ++ms)
            acc[0][ms] = __builtin_amdgcn_mfma_f32_16x16x32_bf16(vf0, pf[ms], acc[0][ms], 0, 0, 0);
#pragma unroll
        for (int ms = 0; ms < 4; ++ms)
            acc[1][ms] = __builtin_amdgcn_mfma_f32_16x16x32_bf16(vf1, pf[ms], acc[1][ms], 0, 0, 0);

        kf0 = kf0n; kf1 = kf1n; vf0 = vf0n; vf1 = vf1n;
    }

    // share per-column softmax denominators across waves
    if (grp == 0) lrow[wu * 16 + col] = l_run;
    __syncthreads();

    const float g = gamma[0];
#pragma unroll
    for (int ms = 0; ms < 4; ++ms) {
        float rl = 1.f / lrow[ms * 16 + col];
        int m = m0 + ms * 16 + col;
#pragma unroll
        for (int ct = 0; ct < 2; ++ct)
#pragma unroll
            for (int r = 0; r < 4; ++r) {
                int c = ch * 128 + wu * 32 + ct * 16 + grp * 4 + r;
                size_t idx = ((size_t)b * C_ + c) * N_ + m;
                out[idx] = g * acc[ct][ms][r] * rl + feat[idx];
            }
    }
}

// ---------------------------------------------------------------------------
extern "C" void kernel_launch(void* const* d_in, const int* in_sizes, int n_in,
                              void* d_out, int out_size, void* d_ws, size_t ws_size,
                              hipStream_t stream)
{
    (void)in_sizes; (void)n_in; (void)out_size; (void)ws_size;
    const float* feat  = (const float*)d_in[0];
    const float* w1    = (const float*)d_in[1];
    const float* b1    = (const float*)d_in[2];
    const float* w2    = (const float*)d_in[3];
    const float* b2    = (const float*)d_in[4];
    const float* w3    = (const float*)d_in[5];
    const float* b3    = (const float*)d_in[6];
    const float* gamma = (const float*)d_in[7];
    float* out = (float*)d_out;

    // ws carve (bytes):
    // featT 20,971,520 | wqk 36,864 | w3t 163,840 | qT 2,097,152
    // kfrag 2,097,152 | vfrag 16,777,216  => 42,143,744 total
    unsigned short* featT = (unsigned short*)d_ws;
    unsigned short* wqk   = featT + (size_t)B_ * 8 * N_ * FP;
    unsigned short* w3t   = wqk + 18432;
    unsigned short* qT    = w3t + (size_t)8 * 256 * FP;
    unsigned short* kfrag = qT + (size_t)B_ * N_ * 32;
    unsigned short* vfrag = kfrag + (size_t)B_ * 128 * 2 * 512;

    prep<<<2048 + 32, 256, 0, stream>>>(feat, w1, w2, w3, featT, wqk, w3t);
    proj<<<768, 256, 0, stream>>>(featT, wqk, w3t, b1, b2, b3, qT, kfrag, vfrag);
    attn<<<dim3(64, B_, 2), 256, 0, stream>>>(qT, kfrag, vfrag, feat, gamma, out);
}

// Round 7
// 213.736 us; speedup vs baseline: 1.0705x; 1.0705x over previous
//
#include <hip/hip_runtime.h>
#include <hip/hip_bf16.h>
#include <math.h>

// Problem constants: B=8, C=256, CQ=32, N=H*W=4096
constexpr int B_ = 8;
constexpr int C_ = 256;
constexpr int CQ_ = 32;
constexpr int N_ = 4096;
constexpr int FP = 40;            // padded pitch (shorts) for 32-wide rows: bank-clean

typedef __attribute__((ext_vector_type(8))) short short8;   // 8 bf16
typedef __attribute__((ext_vector_type(4))) float f32x4;    // MFMA C/D

__device__ __forceinline__ unsigned short pk1(float a) {
    __hip_bfloat16 h = __float2bfloat16(a);
    return *reinterpret_cast<unsigned short*>(&h);
}
__device__ __forceinline__ unsigned pk2(float a, float b) {
    __hip_bfloat162 h = __float22bfloat162_rn(float2{a, b});
    return *reinterpret_cast<unsigned*>(&h);
}

// async global->LDS, 16B per lane (dest = wave-uniform base + lane*16)
__device__ __forceinline__ void async16(const unsigned short* g, unsigned short* l) {
    __builtin_amdgcn_global_load_lds(
        (const __attribute__((address_space(1))) unsigned int*)g,
        (__attribute__((address_space(3))) unsigned int*)l, 16, 0, 0);
}

// ---------------------------------------------------------------------------
// prep (merged): blocks 0..2047 transpose feat -> featT [b][ks][n][ci&31] pitch 40
// (b = id%8 for XCD affinity); blocks 2048..2079: w1/w2 -> wqk pitch 264,
// w3 -> w3t [ks][c][ci&31] pitch 40.
// ---------------------------------------------------------------------------
__global__ __launch_bounds__(256) void prep(
    const float* __restrict__ feat,
    const float* __restrict__ w1, const float* __restrict__ w2,
    const float* __restrict__ w3,
    unsigned short* __restrict__ featT,
    unsigned short* __restrict__ wqk, unsigned short* __restrict__ w3t)
{
    __shared__ float sh[64][65];
    int id = blockIdx.x;
    int t = threadIdx.x;

    if (id < 2048) {
        int b = id & 7, r = id >> 3;           // id%8==b -> XCD affinity
        int n0 = (r >> 2) * 64, c0 = (r & 3) * 64;
        int cl = t >> 4, n4 = (t & 15) * 4;
#pragma unroll
        for (int i = 0; i < 4; ++i) {
            int c = cl + i * 16;
            float4 fv = *reinterpret_cast<const float4*>(
                &feat[((size_t)b * C_ + c0 + c) * N_ + n0 + n4]);
            sh[c][n4 + 0] = fv.x; sh[c][n4 + 1] = fv.y;
            sh[c][n4 + 2] = fv.z; sh[c][n4 + 3] = fv.w;
        }
        __syncthreads();
        int c2 = (t & 31) * 2, nb = t >> 5;
#pragma unroll
        for (int j = 0; j < 8; ++j) {
            int n = nb + j * 8;
            unsigned pv = pk2(sh[c2][n], sh[c2 + 1][n]);
            int cg = c0 + c2;
            int ks = cg >> 5, cij = cg & 31;
            *reinterpret_cast<unsigned*>(
                &featT[(((size_t)b * 8 + ks) * N_ + n0 + n) * FP + cij]) = pv;
        }
    } else {
        int tid = (id - 2048) * 256 + t;
        const int stride = 32 * 256;
        for (int f = tid; f < 2 * 32 * 256; f += stride) {
            int mat = f >> 13, rest = f & 8191;
            int o = rest >> 8, ci = rest & 255;
            const float* w = mat ? w2 : w1;
            wqk[(mat * 32 + o) * 264 + ci] = pk1(w[o * 256 + ci]);
        }
        for (int f = tid; f < 256 * 256; f += stride) {
            int c = f >> 8, ci = f & 255;
            w3t[((size_t)(ci >> 5) * 256 + c) * FP + (ci & 31)] = pk1(w3[f]);
        }
    }
}

// ---------------------------------------------------------------------------
// proj (merged): blocks 0..255 = qk (b = id%8, 128 n rows) -> qT + kfrag;
//                blocks 256..767 = v (b = (id-256)%8, 64-n tile) -> vfrag.
// kfrag[b][t32][sub2][lane64][8]: lane (col,grp) holds K[n=t*32+sub*16+col][cq=grp*8+j]
// vfrag[b][t32][cg16][lane64][8]: lane (col,grp) holds V[c=cg*16+col][nloc=grp*8+j]
// ---------------------------------------------------------------------------
__global__ __launch_bounds__(256) void proj(
    const unsigned short* __restrict__ featT, const unsigned short* __restrict__ wqk,
    const unsigned short* __restrict__ w3t,
    const float* __restrict__ b1, const float* __restrict__ b2,
    const float* __restrict__ b3,
    unsigned short* __restrict__ qT, unsigned short* __restrict__ kfrag,
    unsigned short* __restrict__ vfrag)
{
    __shared__ __align__(16) unsigned short smem[23552];   // 47,104 B
    int id = blockIdx.x;
    int t = threadIdx.x, lane = t & 63;
    int wu = t >> 6, col = lane & 15, grp = lane >> 4;

    if (id < 256) {
        // ---------------- qk branch ----------------
        unsigned short* wsl = smem;           // 18,432 shorts (pitch 264)
        unsigned short* fa  = smem + 18432;   //  5,120 shorts (128 rows x 40)
        int b = id & 7, n0 = (id >> 3) * 128;  // id%8==b -> XCD affinity

#pragma unroll
        for (int i = 0; i < 9; ++i)
            async16(wqk + wu * 4608 + i * 512 + lane * 8, wsl + wu * 4608 + i * 512);

        f32x4 acc[2][2][2];  // [msub][mat][ot]
#pragma unroll
        for (int ms = 0; ms < 2; ++ms)
#pragma unroll
            for (int ot = 0; ot < 2; ++ot) {
                float bq = b1[ot * 16 + col];
                float bk = b2[ot * 16 + col];
                acc[ms][0][ot] = (f32x4){bq, bq, bq, bq};
                acc[ms][1][ot] = (f32x4){bk, bk, bk, bk};
            }

        for (int ks = 0; ks < 8; ++ks) {
            __syncthreads();
            const unsigned short* src = featT + (((size_t)b * 8 + ks) * N_ + n0) * FP;
            // 128*40 = 5120 shorts = 10 chunks of 512
#pragma unroll
            for (int i = 0; i < 3; ++i) {
                int ch = i * 4 + wu;
                if (ch < 10) async16(src + ch * 512 + lane * 8, fa + ch * 512);
            }
            __syncthreads();

            short8 a[2], bf[2][2];
#pragma unroll
            for (int ms = 0; ms < 2; ++ms)
                a[ms] = *(const short8*)&fa[(wu * 32 + ms * 16 + col) * FP + grp * 8];
#pragma unroll
            for (int mat = 0; mat < 2; ++mat)
#pragma unroll
                for (int ot = 0; ot < 2; ++ot)
                    bf[mat][ot] = *(const short8*)
                        &wsl[(mat * 32 + ot * 16 + col) * 264 + ks * 32 + grp * 8];
#pragma unroll
            for (int ms = 0; ms < 2; ++ms)
#pragma unroll
                for (int mat = 0; mat < 2; ++mat)
#pragma unroll
                    for (int ot = 0; ot < 2; ++ot)
                        acc[ms][mat][ot] = __builtin_amdgcn_mfma_f32_16x16x32_bf16(
                            a[ms], bf[mat][ot], acc[ms][mat][ot], 0, 0, 0);
        }

#pragma unroll
        for (int ms = 0; ms < 2; ++ms)
#pragma unroll
            for (int ot = 0; ot < 2; ++ot)
#pragma unroll
                for (int r = 0; r < 4; ++r) {
                    int n = n0 + wu * 32 + ms * 16 + grp * 4 + r;
                    int o = ot * 16 + col;
                    qT[((size_t)b * N_ + n) * 32 + o] = pk1(acc[ms][0][ot][r]);
                    // kfrag scatter: tile=n>>5, sub=(n>>4)&1, lane'=(o>>3)*16+(n&15), j=o&7
                    kfrag[(((size_t)b * 128 + (n >> 5)) * 2 + ((n >> 4) & 1)) * 512
                          + ((o >> 3) * 16 + (n & 15)) * 8 + (o & 7)]
                        = pk1(acc[ms][1][ot][r]);
                }
    } else {
        // ---------------- v branch ----------------
        unsigned short* w3s = smem;           // 10,240 shorts (256 rows x 40)
        unsigned short* fb  = smem + 10240;   //  2,560 shorts (64 rows x 40)
        int vid = id - 256;
        int b = vid & 7, tile = vid >> 3, n0 = tile * 64;  // id%8==b (256%8==0)

        f32x4 acc[4][4];  // [ct][nsub]
#pragma unroll
        for (int ct = 0; ct < 4; ++ct) {
            int c = wu * 64 + ct * 16 + grp * 4;
            float4 bb = *(const float4*)&b3[c];
            f32x4 ini = (f32x4){bb.x, bb.y, bb.z, bb.w};
#pragma unroll
            for (int ns = 0; ns < 4; ++ns) acc[ct][ns] = ini;
        }

        for (int ks = 0; ks < 8; ++ks) {
            __syncthreads();
            const unsigned short* wsrc = w3t + (size_t)ks * 256 * FP;
#pragma unroll
            for (int i = 0; i < 5; ++i) {
                int ch = wu * 5 + i;
                async16(wsrc + ch * 512 + lane * 8, w3s + ch * 512);
            }
            const unsigned short* fsrc = featT + (((size_t)b * 8 + ks) * N_ + n0) * FP;
#pragma unroll
            for (int i = 0; i < 2; ++i) {
                int ch = i * 4 + wu;
                if (ch < 5) async16(fsrc + ch * 512 + lane * 8, fb + ch * 512);
            }
            __syncthreads();

            short8 a[4], bfr[4];
#pragma unroll
            for (int ct = 0; ct < 4; ++ct)
                a[ct] = *(const short8*)&w3s[(wu * 64 + ct * 16 + col) * FP + grp * 8];
#pragma unroll
            for (int ns = 0; ns < 4; ++ns)
                bfr[ns] = *(const short8*)&fb[(ns * 16 + col) * FP + grp * 8];
#pragma unroll
            for (int ct = 0; ct < 4; ++ct)
#pragma unroll
                for (int ns = 0; ns < 4; ++ns)
                    acc[ct][ns] = __builtin_amdgcn_mfma_f32_16x16x32_bf16(
                        a[ct], bfr[ns], acc[ct][ns], 0, 0, 0);
        }

        // vfrag scatter: vt=n>>5, cg=c>>4, lane'=((n>>3)&3)*16+(c&15), j=n&7
#pragma unroll
        for (int ct = 0; ct < 4; ++ct)
#pragma unroll
            for (int ns = 0; ns < 4; ++ns)
#pragma unroll
                for (int r = 0; r < 4; ++r) {
                    int c = wu * 64 + ct * 16 + grp * 4 + r;
                    int n = n0 + ns * 16 + col;
                    vfrag[((((size_t)b * 128 + (n >> 5)) * 16 + (c >> 4)) * 64
                           + ((n >> 3) & 3) * 16 + (c & 15)) * 8 + (n & 7)]
                        = pk1(acc[ct][ns][r]);
                }
    }
}

// ---------------------------------------------------------------------------
// attn tile body: S^T -> exp -> P to LDS -> (K prefetch) -> light barrier ->
// PV MFMA -> (V prefetch). Prefetch distance = 2 tiles (two reg sets, unroll 2).
// ---------------------------------------------------------------------------
__device__ __forceinline__ void attn_tile(
    short8& kf0, short8& kf1, short8& vf0, short8& vf1,
    const short8 qf, unsigned short* psb,
    const unsigned short* kb, const unsigned short* vb, int tn,
    f32x4 acc[2][4], float& l_run, int col, int grp, int wu)
{
    constexpr int PP = 40;
    f32x4 z = (f32x4){0.f, 0.f, 0.f, 0.f};
    f32x4 d0 = __builtin_amdgcn_mfma_f32_16x16x32_bf16(kf0, qf, z, 0, 0, 0);
    f32x4 d1 = __builtin_amdgcn_mfma_f32_16x16x32_bf16(kf1, qf, z, 0, 0, 0);

    float p0 = __expf(d0[0]), p1 = __expf(d0[1]);
    float p2 = __expf(d0[2]), p3 = __expf(d0[3]);
    float p4 = __expf(d1[0]), p5 = __expf(d1[1]);
    float p6 = __expf(d1[2]), p7 = __expf(d1[3]);
    l_run += ((p0 + p1) + (p2 + p3)) + ((p4 + p5) + (p6 + p7));  // partial: own grp slice

    uint2 w0; w0.x = pk2(p0, p1); w0.y = pk2(p2, p3);
    uint2 w1; w1.x = pk2(p4, p5); w1.y = pk2(p6, p7);
    unsigned short* pw = psb + (wu * 16 + col) * PP;
    *reinterpret_cast<uint2*>(pw + grp * 4)      = w0;
    *reinterpret_cast<uint2*>(pw + 16 + grp * 4) = w1;

    // prefetch K(tn) — rides through the barrier (no vmcnt drain)
    kf0 = *(const short8*)(kb + (size_t)tn * 1024);
    kf1 = *(const short8*)(kb + (size_t)tn * 1024 + 512);

    __asm__ volatile("s_waitcnt lgkmcnt(0)\n\ts_barrier" ::: "memory");

#pragma unroll
    for (int ms = 0; ms < 4; ++ms) {
        short8 pf = *(const short8*)(psb + (ms * 16 + col) * PP + grp * 8);
        acc[0][ms] = __builtin_amdgcn_mfma_f32_16x16x32_bf16(vf0, pf, acc[0][ms], 0, 0, 0);
        acc[1][ms] = __builtin_amdgcn_mfma_f32_16x16x32_bf16(vf1, pf, acc[1][ms], 0, 0, 0);
    }

    // prefetch V(tn)
    vf0 = *(const short8*)(vb + (size_t)tn * 8192);
    vf1 = *(const short8*)(vb + (size_t)tn * 8192 + 512);
}

// ---------------------------------------------------------------------------
// attn: flash attention, no-max softmax, fragment-image global->VGPR loads,
// ps double-buffered, one lgkm-only barrier per tile, prefetch distance 2.
// Grid dim3(8=b, 64=m-tile, 2=c-half): linear id % 8 == b -> XCD affinity.
// ---------------------------------------------------------------------------
__global__ __launch_bounds__(256, 4) void attn(
    const unsigned short* __restrict__ qT, const unsigned short* __restrict__ kfrag,
    const unsigned short* __restrict__ vfrag, const float* __restrict__ feat,
    const float* __restrict__ gamma, float* __restrict__ out)
{
    constexpr int PP = 40;
    __shared__ __align__(16) unsigned short ps[2][64 * PP];  // 10,240 B
    __shared__ float lrow[64];

    const int b  = blockIdx.x;                 // fastest dim -> id%8==b
    const int m0 = blockIdx.y * 64;
    const int ch = blockIdx.z;                 // channel half (128 c)
    int t0 = threadIdx.x, lane = t0 & 63;
    int wu = t0 >> 6, col = lane & 15, grp = lane >> 4;

    const int m_own = m0 + wu * 16 + col;
    short8 qf = *(const short8*)&qT[((size_t)b * N_ + m_own) * 32 + grp * 8];

    const int cgb = ch * 8 + wu * 2;           // wave's first 16-ch V group
    const unsigned short* kb = kfrag + (size_t)b * 128 * 1024 + lane * 8;
    const unsigned short* vb = vfrag + ((size_t)b * 128 * 16 + cgb) * 512 + lane * 8;

    f32x4 acc[2][4];   // [ct][msub]
#pragma unroll
    for (int i = 0; i < 2; ++i)
#pragma unroll
        for (int j = 0; j < 4; ++j) acc[i][j] = (f32x4){0.f, 0.f, 0.f, 0.f};
    float l_run = 0.f;

    // prologue: set A = tile 0, set B = tile 1
    short8 kA0 = *(const short8*)(kb);
    short8 kA1 = *(const short8*)(kb + 512);
    short8 vA0 = *(const short8*)(vb);
    short8 vA1 = *(const short8*)(vb + 512);
    short8 kB0 = *(const short8*)(kb + 1024);
    short8 kB1 = *(const short8*)(kb + 1536);
    short8 vB0 = *(const short8*)(vb + 8192);
    short8 vB1 = *(const short8*)(vb + 8192 + 512);

    for (int tp = 0; tp < 128; tp += 2) {
        attn_tile(kA0, kA1, vA0, vA1, qf, ps[0], kb, vb, (tp + 2) & 127,
                  acc, l_run, col, grp, wu);
        attn_tile(kB0, kB1, vB0, vB1, qf, ps[1], kb, vb, (tp + 3) & 127,
                  acc, l_run, col, grp, wu);
    }

    // finish per-m softmax denominator: butterfly across the 4 lane-groups
    l_run += __shfl_xor(l_run, 16);
    l_run += __shfl_xor(l_run, 32);
    if (grp == 0) lrow[wu * 16 + col] = l_run;
    __syncthreads();

    const float g = gamma[0];
#pragma unroll
    for (int ms = 0; ms < 4; ++ms) {
        float rl = 1.f / lrow[ms * 16 + col];
        int m = m0 + ms * 16 + col;
#pragma unroll
        for (int ct = 0; ct < 2; ++ct)
#pragma unroll
            for (int r = 0; r < 4; ++r) {
                int c = ch * 128 + wu * 32 + ct * 16 + grp * 4 + r;
                size_t idx = ((size_t)b * C_ + c) * N_ + m;
                out[idx] = g * acc[ct][ms][r] * rl + feat[idx];
            }
    }
}

// ---------------------------------------------------------------------------
extern "C" void kernel_launch(void* const* d_in, const int* in_sizes, int n_in,
                              void* d_out, int out_size, void* d_ws, size_t ws_size,
                              hipStream_t stream)
{
    (void)in_sizes; (void)n_in; (void)out_size; (void)ws_size;
    const float* feat  = (const float*)d_in[0];
    const float* w1    = (const float*)d_in[1];
    const float* b1    = (const float*)d_in[2];
    const float* w2    = (const float*)d_in[3];
    const float* b2    = (const float*)d_in[4];
    const float* w3    = (const float*)d_in[5];
    const float* b3    = (const float*)d_in[6];
    const float* gamma = (const float*)d_in[7];
    float* out = (float*)d_out;

    // ws carve (bytes):
    // featT 20,971,520 | wqk 36,864 | w3t 163,840 | qT 2,097,152
    // kfrag 2,097,152 | vfrag 16,777,216  => 42,143,744 total
    unsigned short* featT = (unsigned short*)d_ws;
    unsigned short* wqk   = featT + (size_t)B_ * 8 * N_ * FP;
    unsigned short* w3t   = wqk + 18432;
    unsigned short* qT    = w3t + (size_t)8 * 256 * FP;
    unsigned short* kfrag = qT + (size_t)B_ * N_ * 32;
    unsigned short* vfrag = kfrag + (size_t)B_ * 128 * 2 * 512;

    prep<<<2048 + 32, 256, 0, stream>>>(feat, w1, w2, w3, featT, wqk, w3t);
    proj<<<768, 256, 0, stream>>>(featT, wqk, w3t, b1, b2, b3, qT, kfrag, vfrag);
    attn<<<dim3(8, 64, 2), 256, 0, stream>>>(qT, kfrag, vfrag, feat, gamma, out);
}